// Round 8
// baseline (236.283 us; speedup 1.0000x reference)
//
#include <hip/hip_runtime.h>
#include <hip/hip_bf16.h>
#include <math.h>

typedef __bf16 bf16_t;
typedef __bf16 bf16x8 __attribute__((ext_vector_type(8)));
typedef float floatx4 __attribute__((ext_vector_type(4)));
typedef unsigned int uintx4 __attribute__((ext_vector_type(4)));

#define S_LEN 4096
#define DMODEL 1024
#define NH 16
#define DK 64
#define WELEM (DMODEL * DMODEL)
// 0.125 (1/sqrt(dk)) * log2(e): folded into RoPE'd Q (r13-validated)
#define SCALE_LOG2E 0.1803368801111204f

#define QBM 128
#define QBN 128
#define BM 128
#define BN 64

static __device__ __forceinline__ floatx4 mfma16(bf16x8 a, bf16x8 b, floatx4 c) {
  return __builtin_amdgcn_mfma_f32_16x16x32_bf16(a, b, c, 0, 0, 0);
}

// Raw barrier with lgkm-only wait (attn): NO vmcnt drain.
static __device__ __forceinline__ void barrier_lgkm() {
  __builtin_amdgcn_sched_barrier(0);
  __asm__ volatile("s_waitcnt lgkmcnt(0)" ::: "memory");
  __builtin_amdgcn_s_barrier();
  __builtin_amdgcn_sched_barrier(0);
}

// Counted-vmcnt barrier (GEMMs): wait my oldest staging loads, then sync.
#define VMCNT_BARRIER(N)                                         \
  do {                                                           \
    __builtin_amdgcn_sched_barrier(0);                           \
    __asm__ volatile("s_waitcnt vmcnt(" #N ")" ::: "memory");    \
    __builtin_amdgcn_s_barrier();                                \
    __builtin_amdgcn_sched_barrier(0);                           \
  } while (0)

// global -> LDS direct 16B/lane (wave-uniform LDS base; HW adds lane*16).
typedef __attribute__((address_space(3))) unsigned int lds_u32_t;
typedef __attribute__((address_space(1))) const unsigned int glb_u32_t;
static __device__ __forceinline__ void gll16(const void* g, void* l) {
  __builtin_amdgcn_global_load_lds((glb_u32_t*)g, (lds_u32_t*)l, 16, 0, 0);
}

// bf16 pair pack (truncation — same rounding as the validated >>16 path).
static __device__ __forceinline__ unsigned int packbf(float a, float b) {
  return (__float_as_uint(a) >> 16) | (__float_as_uint(b) & 0xffff0000u);
}

// Paired cross-quad word exchanges (gfx950 permlane*_swap).
static __device__ __forceinline__ void swap32(unsigned int& a, unsigned int& b) {
  auto r = __builtin_amdgcn_permlane32_swap(a, b, false, false);
  a = r[0]; b = r[1];
}
static __device__ __forceinline__ void swap16(unsigned int& a, unsigned int& b) {
  auto r = __builtin_amdgcn_permlane16_swap(a, b, false, false);
  a = r[0]; b = r[1];
}

// Per-tile chunk compute (r21-validated): swapped QK, exp2, causal mask,
// lane-local lsum, bf16 pack + 4x4 cross-quad permlane transpose.
#define QK_SOFTMAX(QF0, QF1, LSUM, PF0, PF1, Q0, MASKED)                     \
  {                                                                          \
    floatx4 s_[4];                                                           \
    __builtin_amdgcn_s_setprio(1);                                           \
    _Pragma("unroll")                                                        \
    for (int f_ = 0; f_ < 4; ++f_) {                                         \
      floatx4 z_ = {0.f, 0.f, 0.f, 0.f};                                     \
      z_ = mfma16(kf[f_][0], QF0, z_);                                       \
      s_[f_] = mfma16(kf[f_][1], QF1, z_);                                   \
    }                                                                        \
    __builtin_amdgcn_s_setprio(0);                                           \
    unsigned int w_[4][2];                                                   \
    _Pragma("unroll")                                                        \
    for (int f_ = 0; f_ < 4; ++f_) {                                         \
      float pe_[4];                                                          \
      _Pragma("unroll")                                                      \
      for (int r_ = 0; r_ < 4; ++r_) {                                       \
        float v_ = __builtin_amdgcn_exp2f(s_[f_][r_]);                       \
        if (MASKED) {                                                        \
          int kv_ = kvb + f_ * 16 + quad * 4 + r_;                           \
          v_ = (kv_ <= (Q0) + lr) ? v_ : 0.f;                                \
        }                                                                    \
        LSUM += v_;                                                          \
        pe_[r_] = v_;                                                        \
      }                                                                      \
      w_[f_][0] = packbf(pe_[0], pe_[1]);                                    \
      w_[f_][1] = packbf(pe_[2], pe_[3]);                                    \
    }                                                                        \
    swap32(w_[0][0], w_[1][0]); swap16(w_[0][0], w_[1][0]);                  \
    swap32(w_[0][1], w_[1][1]); swap16(w_[0][1], w_[1][1]);                  \
    swap32(w_[2][0], w_[3][0]); swap16(w_[2][0], w_[3][0]);                  \
    swap32(w_[2][1], w_[3][1]); swap16(w_[2][1], w_[3][1]);                  \
    uintx4 u0_ = {w_[0][0], w_[0][1], w_[1][0], w_[1][1]};                   \
    uintx4 u1_ = {w_[2][0], w_[2][1], w_[3][0], w_[3][1]};                   \
    __builtin_memcpy(&PF0, &u0_, 16);                                        \
    __builtin_memcpy(&PF1, &u1_, 16);                                        \
  }

// Merged fp32->bf16 convert: blocks 0..2047 convert x (4M elems), blocks
// 2048..3583 convert Wq/Wk/Wv (1M each, 512 blocks per weight).
__global__ __launch_bounds__(256) void conv_all(const float* __restrict__ x,
                                                const float* __restrict__ Wq,
                                                const float* __restrict__ Wk,
                                                const float* __restrict__ Wv,
                                                bf16_t* __restrict__ xb,
                                                bf16_t* __restrict__ WB) {
  const int bid = blockIdx.x;
  const float* src;
  bf16_t* dst;
  size_t i;
  if (bid < 2048) {
    src = x; dst = xb;
    i = (size_t)bid * 2048 + threadIdx.x * 8;
  } else {
    const int w = bid - 2048;
    const int sel = w >> 9;
    src = (sel == 0) ? Wq : ((sel == 1) ? Wk : Wv);
    dst = WB + (size_t)sel * WELEM;
    i = (size_t)(w & 511) * 2048 + threadIdx.x * 8;
  }
  float4 a = *(const float4*)(src + i);
  float4 b = *(const float4*)(src + i + 4);
  bf16x8 v;
  v[0] = (bf16_t)a.x; v[1] = (bf16_t)a.y; v[2] = (bf16_t)a.z; v[3] = (bf16_t)a.w;
  v[4] = (bf16_t)b.x; v[5] = (bf16_t)b.y; v[6] = (bf16_t)b.z; v[7] = (bf16_t)b.w;
  *(bf16x8*)(dst + i) = v;
}

// Single-weight convert (Wo, post-attn — WoB aliases Qb so it cannot run
// before attn finishes reading Q).
__global__ __launch_bounds__(256) void wcvt1(const float* __restrict__ W,
                                             bf16_t* __restrict__ dst) {
  size_t i = ((size_t)blockIdx.x * 256 + threadIdx.x) * 8;
  float4 a = *(const float4*)(W + i);
  float4 b = *(const float4*)(W + i + 4);
  bf16x8 v;
  v[0] = (bf16_t)a.x; v[1] = (bf16_t)a.y; v[2] = (bf16_t)a.z; v[3] = (bf16_t)a.w;
  v[4] = (bf16_t)b.x; v[5] = (bf16_t)b.y; v[6] = (bf16_t)b.z; v[7] = (bf16_t)b.w;
  *(bf16x8*)(dst + i) = v;
}

// FUSED QKV GEMM + RoPE, r24: r23's gll/3-slot-ring/counted-vmcnt structure,
// with RoPE applied in the epilogue for sel<2 (rotation pairs are adjacent
// lanes: one shfl_xor(.,1) + sincos per element, Q pre-scaled by SCALE_LOG2E).
// Deletes the separate rope kernel and its 32MB round-trip; Q/K also skip one
// bf16 round-trip (rotation on fp32 acc).
__global__ __launch_bounds__(256, 3) void qkv_gemm(const bf16_t* __restrict__ A,
                                                   const bf16_t* __restrict__ WB,
                                                   bf16_t* __restrict__ Qo,
                                                   bf16_t* __restrict__ Ko,
                                                   bf16_t* __restrict__ Vo,
                                                   const void* __restrict__ posv) {
  // 3 slots x {A[128][64B] | B[128][64B]} = 3 x 16 KB
  __shared__ __align__(16) unsigned char smem[49152];

  const int tid  = threadIdx.x;
  const int wid  = tid >> 6;
  const int lane = tid & 63;
  const int lr   = lane & 15;
  const int quad = lane >> 4;
  const int wm = wid >> 1, wn = wid & 1;
  const int sel = blockIdx.x >> 3;              // 0=Q, 1=K, 2=V
  const int n0  = (blockIdx.x & 7) * QBN;
  const int m0  = blockIdx.y * QBM;
  const bf16_t* Bsrc = WB + (size_t)sel * WELEM;

  const int mat  = wid >> 1;                 // 0=A, 1=B
  const int lrow = lane >> 2;                // 0..15
  const int swzl = ((lane & 3) * 16) ^ ((lrow & 3) << 4);
  const unsigned char* gbase =
      (const unsigned char*)(mat ? Bsrc : A) +
      (size_t)((mat ? n0 : m0) + (wid & 1) * 64 + lrow) * (DMODEL * 2) + swzl;
  const int lds_w = mat * 8192 + (wid & 1) * 4096;  // + k*1024 + slot*16384

  floatx4 acc[4][4];
#pragma unroll
  for (int i = 0; i < 4; ++i)
#pragma unroll
    for (int j = 0; j < 4; ++j) acc[i][j] = floatx4{0.f, 0.f, 0.f, 0.f};

  // prologue: K-steps 0,1 into slots 0,1
#pragma unroll
  for (int st = 0; st < 2; ++st) {
    const unsigned char* gs = gbase + st * 64;
    unsigned char* ls = smem + st * 16384 + lds_w;
#pragma unroll
    for (int k = 0; k < 4; ++k)
      gll16(gs + (size_t)k * (16 * 2048), ls + k * 1024);
  }

  const int frsw = 16 * (quad ^ (lr & 3));
  int csl = 0, isl = 2;
  for (int it = 0; it < 32; ++it) {
    VMCNT_BARRIER(4);   // my step-it loads landed; barrier -> everyone's

    {  // issue step it+2 into slot isl (freed by the barrier above)
      int sd = it + 2; if (sd > 31) sd = 31;
      const unsigned char* gs = gbase + sd * 64;
      unsigned char* ls = smem + isl * 16384 + lds_w;
#pragma unroll
      for (int k = 0; k < 4; ++k)
        gll16(gs + (size_t)k * (16 * 2048), ls + k * 1024);
    }

    const unsigned char* As_ = smem + csl * 16384;
    bf16x8 af[4], bfr[4];
#pragma unroll
    for (int i = 0; i < 4; ++i)
      af[i] = *(const bf16x8*)(As_ + (wm * 64 + i * 16 + lr) * 64 + frsw);
#pragma unroll
    for (int j = 0; j < 4; ++j)
      bfr[j] = *(const bf16x8*)(As_ + 8192 + (wn * 64 + j * 16 + lr) * 64 + frsw);

    __builtin_amdgcn_s_setprio(1);
#pragma unroll
    for (int i = 0; i < 4; ++i)
#pragma unroll
      for (int j = 0; j < 4; ++j)
        acc[i][j] = mfma16(af[i], bfr[j], acc[i][j]);
    __builtin_amdgcn_s_setprio(0);

    csl = (csl == 2) ? 0 : csl + 1;
    isl = (isl == 2) ? 0 : isl + 1;
  }

  if (sel < 2) {
    // ---- fused RoPE epilogue (rope_kernel math, r13-validated) ----
    bf16_t* Cn = (sel == 0) ? Qo : Ko;
    const long long* p64 = (const long long*)posv;
    const int*       p32 = (const int*)posv;
    unsigned long long w0 = (unsigned long long)p64[0];
    unsigned long long w1 = (unsigned long long)p64[1];
    const bool is64 = ((w0 >> 32) == 0ull) && ((w1 >> 32) == 0ull);
    const float qs  = (sel == 0) ? SCALE_LOG2E : 1.0f;
    const float sgn = (lane & 1) ? 1.0f : -1.0f;

    // rotation index u = (col&63)>>1 = j*8 + (lr>>1); 4 inv_freqs per thread
    float invf[4];
#pragma unroll
    for (int j = 0; j < 4; ++j)
      invf[j] = expf(-(float)(j * 8 + (lr >> 1)) * (9.210340371976184f / 32.0f));

#pragma unroll
    for (int i = 0; i < 4; ++i) {
#pragma unroll
      for (int r = 0; r < 4; ++r) {
        const int row = m0 + wm * 64 + i * 16 + quad * 4 + r;
        long long v64 = p64[is64 ? row : 0];
        const float p = is64 ? (float)v64 : (float)p32[row];
#pragma unroll
        for (int j = 0; j < 4; ++j) {
          float my    = acc[i][j][r];
          float other = __shfl_xor(my, 1, 64);
          float sn, cs;
          sincosf(p * invf[j], &sn, &cs);
          float v = (my * cs + sgn * other * sn) * qs;
          int col = n0 + wn * 64 + j * 16 + lr;
          Cn[(size_t)row * DMODEL + col] = (bf16_t)v;
        }
      }
    }
  } else {
#pragma unroll
    for (int i = 0; i < 4; ++i)
#pragma unroll
      for (int j = 0; j < 4; ++j)
#pragma unroll
        for (int r = 0; r < 4; ++r) {
          int row = m0 + wm * 64 + i * 16 + quad * 4 + r;
          int col = n0 + wn * 64 + j * 16 + lr;
          Vo[(size_t)col * S_LEN + row] = (bf16_t)acc[i][j][r];
        }
  }
}

// Final GEMM, r23 structure: gll + 3-slot ring + counted vmcnt(3).
__global__ __launch_bounds__(256, 2) void gemm_out(const bf16_t* __restrict__ A,
                                                   const bf16_t* __restrict__ B,
                                                   float* __restrict__ C,
                                                   int M, int N, int Kd) {
  __shared__ __align__(16) unsigned char smem[36864];

  const int tid  = threadIdx.x;
  const int wid  = tid >> 6;
  const int lane = tid & 63;
  const int lr   = lane & 15;
  const int quad = lane >> 4;
  const int wm = wid >> 1, wn = wid & 1;
  const int m0 = blockIdx.y * BM;
  const int n0 = blockIdx.x * BN;
  const int NIT = Kd >> 5;                 // 32

  const int lrow = lane >> 2;
  const int swzl = ((lane & 3) * 16) ^ ((lrow & 3) << 4);
  const unsigned char* gk[3];
  int lo[3];
#pragma unroll
  for (int k = 0; k < 3; ++k) {
    int id = wid * 3 + k;
    bool mb = id >= 8;
    int r = (id - (mb ? 8 : 0)) * 16 + lrow;
    gk[k] = (const unsigned char*)(mb ? B : A) +
            (size_t)((mb ? n0 : m0) + r) * ((size_t)Kd * 2) + swzl;
    lo[k] = mb ? (8192 + (id - 8) * 1024) : (id * 1024);
  }

  floatx4 acc[4][2];
#pragma unroll
  for (int i = 0; i < 4; ++i)
#pragma unroll
    for (int j = 0; j < 2; ++j) acc[i][j] = floatx4{0.f, 0.f, 0.f, 0.f};

#pragma unroll
  for (int st = 0; st < 2; ++st) {
    unsigned char* ls = smem + st * 12288;
#pragma unroll
    for (int k = 0; k < 3; ++k)
      gll16(gk[k] + st * 64, ls + lo[k]);
  }

  const int frsw = 16 * (quad ^ (lr & 3));
  int csl = 0, isl = 2;
  for (int it = 0; it < NIT; ++it) {
    VMCNT_BARRIER(3);

    {
      int sd = it + 2; if (sd > NIT - 1) sd = NIT - 1;
      unsigned char* ls = smem + isl * 12288;
#pragma unroll
      for (int k = 0; k < 3; ++k)
        gll16(gk[k] + sd * 64, ls + lo[k]);
    }

    const unsigned char* As_ = smem + csl * 12288;
    bf16x8 af[4], bfr[2];
#pragma unroll
    for (int i = 0; i < 4; ++i)
      af[i] = *(const bf16x8*)(As_ + (wm * 64 + i * 16 + lr) * 64 + frsw);
#pragma unroll
    for (int j = 0; j < 2; ++j)
      bfr[j] = *(const bf16x8*)(As_ + 8192 + (wn * 32 + j * 16 + lr) * 64 + frsw);

    __builtin_amdgcn_s_setprio(1);
#pragma unroll
    for (int i = 0; i < 4; ++i)
#pragma unroll
      for (int j = 0; j < 2; ++j)
        acc[i][j] = mfma16(af[i], bfr[j], acc[i][j]);
    __builtin_amdgcn_s_setprio(0);

    csl = (csl == 2) ? 0 : csl + 1;
    isl = (isl == 2) ? 0 : isl + 1;
  }

#pragma unroll
  for (int i = 0; i < 4; ++i)
#pragma unroll
    for (int j = 0; j < 2; ++j)
#pragma unroll
      for (int r = 0; r < 4; ++r) {
        int row = m0 + wm * 64 + i * 16 + quad * 4 + r;
        int col = n0 + wn * 32 + j * 16 + lr;
        C[(size_t)row * N + col] = acc[i][j][r];
      }
}

// Flash attention, r22 structure (UNCHANGED, validated): dual-tile waves,
// in-register P transpose, raw lgkm barriers, reg-prefetch staging.
__global__ __launch_bounds__(256, 2) void attn_kernel(const bf16_t* __restrict__ Q,
                                                      const bf16_t* __restrict__ Kb,
                                                      const bf16_t* __restrict__ Vt,
                                                      bf16_t* __restrict__ O) {
  __shared__ __align__(16) unsigned char smem[32768];

  const int tid  = threadIdx.x;
  const int wid  = tid >> 6;
  const int lane = tid & 63;
  const int lr   = lane & 15;
  const int quad = lane >> 4;

  const int bid = blockIdx.x;
  const int h   = bid & 15;
  const int pid = bid >> 4;    // 0..31

  const int pA = 63 - pid, pB = pid;
  const int maxcA = pA + 1;
  const int maxcB = pB + 1;
  const int nit   = (maxcA + 1) >> 1;
  const int q0A   = pA * 64 + wid * 16;
  const int q0B   = pB * 64 + wid * 16;

  const bf16_t* Kh = Kb + h * DK;
  const bf16_t* Vh = Vt + (size_t)h * DK * S_LEN;

  const int r0  = tid >> 3;
  const int ke  = (tid & 7) * 8;
  const int ls0 = (r0 * 128 + (tid & 7) * 16) ^ ((r0 & 7) << 4);
  const int ls1 = ls0 + 4096;
  const int sw  = (lr & 7) << 4;

  bf16x8 qfA0, qfA1, qfB0, qfB1;
  {
    const bf16_t* Qp = Q + (size_t)(q0A + lr) * DMODEL + h * DK + quad * 8;
    qfA0 = *(const bf16x8*)(Qp);
    qfA1 = *(const bf16x8*)(Qp + 32);
    const bf16_t* Qq = Q + (size_t)(q0B + lr) * DMODEL + h * DK + quad * 8;
    qfB0 = *(const bf16x8*)(Qq);
    qfB1 = *(const bf16x8*)(Qq + 32);
  }

  floatx4 oA[4], oB[4];
#pragma unroll
  for (int dt = 0; dt < 4; ++dt) {
    oA[dt] = floatx4{0.f, 0.f, 0.f, 0.f};
    oB[dt] = floatx4{0.f, 0.f, 0.f, 0.f};
  }
  float lsumA = 0.f, lsumB = 0.f;

  bf16x8 kr[2][2], vr[2][2];
#pragma unroll
  for (int j = 0; j < 2; ++j) {
    const bf16_t* kg = Kh + (size_t)(j * 64 + r0) * DMODEL + ke;
    const bf16_t* vg = Vh + (size_t)r0 * S_LEN + j * 64 + ke;
    kr[j][0] = *(const bf16x8*)(kg);
    kr[j][1] = *(const bf16x8*)(kg + (size_t)32 * DMODEL);
    vr[j][0] = *(const bf16x8*)(vg);
    vr[j][1] = *(const bf16x8*)(vg + (size_t)32 * S_LEN);
  }

  for (int i = 0; i < nit; ++i) {
    barrier_lgkm();
#pragma unroll
    for (int j = 0; j < 2; ++j) {
      unsigned char* Kd = smem + j * 16384;
      *(bf16x8*)(Kd + ls0)        = kr[j][0];
      *(bf16x8*)(Kd + ls1)        = kr[j][1];
      *(bf16x8*)(Kd + 8192 + ls0) = vr[j][0];
      *(bf16x8*)(Kd + 8192 + ls1) = vr[j][1];
    }
    {
      int cn0 = 2 * i + 2; if (cn0 > maxcA - 1) cn0 = maxcA - 1;
      int cn1 = 2 * i + 3; if (cn1 > maxcA - 1) cn1 = maxcA - 1;
      const int cs0[2] = {cn0, cn1};
#pragma unroll
      for (int j = 0; j < 2; ++j) {
        const bf16_t* kg = Kh + (size_t)(cs0[j] * 64 + r0) * DMODEL + ke;
        const bf16_t* vg = Vh + (size_t)r0 * S_LEN + cs0[j] * 64 + ke;
        kr[j][0] = *(const bf16x8*)(kg);
        kr[j][1] = *(const bf16x8*)(kg + (size_t)32 * DMODEL);
        vr[j][0] = *(const bf16x8*)(vg);
        vr[j][1] = *(const bf16x8*)(vg + (size_t)32 * S_LEN);
      }
    }
    barrier_lgkm();

#pragma unroll
    for (int j = 0; j < 2; ++j) {
      const int c = 2 * i + j;
      if (c < maxcA) {
        const int kvb = c * 64;
        unsigned char* Kbuf = smem + j * 16384;
        unsigned char* Vbuf = Kbuf + 8192;

        bf16x8 kf[4][2];
#pragma unroll
        for (int f = 0; f < 4; ++f) {
          const int rowb = (f * 16 + lr) * 128;
          kf[f][0] = *(const bf16x8*)(Kbuf + rowb + ((quad * 16) ^ sw));
          kf[f][1] = *(const bf16x8*)(Kbuf + rowb + ((quad * 16 + 64) ^ sw));
        }

        bf16x8 pfA0, pfA1;
        QK_SOFTMAX(qfA0, qfA1, lsumA, pfA0, pfA1, q0A, (c == maxcA - 1));

        const bool doB = (c < maxcB);
        bf16x8 pfB0, pfB1;
        if (doB) {
          QK_SOFTMAX(qfB0, qfB1, lsumB, pfB0, pfB1, q0B, (c == maxcB - 1));
        }

        __builtin_amdgcn_s_setprio(1);
        if (doB) {
#pragma unroll
          for (int dt = 0; dt < 4; ++dt) {
            const int rowb = (dt * 16 + lr) * 128;
            bf16x8 v0 = *(const bf16x8*)(Vbuf + rowb + ((quad * 16) ^ sw));
            bf16x8 v1 = *(const bf16x8*)(Vbuf + rowb + ((quad * 16 + 64) ^ sw));
            oA[dt] = mfma16(pfA0, v0, oA[dt]);
            oA[dt] = mfma16(pfA1, v1, oA[dt]);
            oB[dt] = mfma16(pfB0, v0, oB[dt]);
            oB[dt] = mfma16(pfB1, v1, oB[dt]);
          }
        } else {
#pragma unroll
          for (int dt = 0; dt < 4; ++dt) {
            const int rowb = (dt * 16 + lr) * 128;
            bf16x8 v0 = *(const bf16x8*)(Vbuf + rowb + ((quad * 16) ^ sw));
            bf16x8 v1 = *(const bf16x8*)(Vbuf + rowb + ((quad * 16 + 64) ^ sw));
            oA[dt] = mfma16(pfA0, v0, oA[dt]);
            oA[dt] = mfma16(pfA1, v1, oA[dt]);
          }
        }
        __builtin_amdgcn_s_setprio(0);
      }
    }
  }

  lsumA += __shfl_xor(lsumA, 16, 64);
  lsumA += __shfl_xor(lsumA, 32, 64);
  lsumB += __shfl_xor(lsumB, 16, 64);
  lsumB += __shfl_xor(lsumB, 32, 64);

  float invA[4], invB[4];
#pragma unroll
  for (int r = 0; r < 4; ++r) {
    invA[r] = 1.0f / __shfl(lsumA, quad * 4 + r, 64);
    invB[r] = 1.0f / __shfl(lsumB, quad * 4 + r, 64);
  }

#pragma unroll
  for (int dt = 0; dt < 4; ++dt)
#pragma unroll
    for (int r = 0; r < 4; ++r) {
      int rowA = q0A + quad * 4 + r;
      O[(size_t)rowA * DMODEL + h * DK + dt * 16 + lr] =
          (bf16_t)(oA[dt][r] * invA[r]);
      int rowB = q0B + quad * 4 + r;
      O[(size_t)rowB * DMODEL + h * DK + dt * 16 + lr] =
          (bf16_t)(oB[dt][r] * invB[r]);
    }
}

extern "C" void kernel_launch(void* const* d_in, const int* in_sizes, int n_in,
                              void* d_out, int out_size, void* d_ws, size_t ws_size,
                              hipStream_t stream) {
  const float* x  = (const float*)d_in[0];
  const float* Wq = (const float*)d_in[1];
  const float* Wk = (const float*)d_in[2];
  const float* Wv = (const float*)d_in[3];
  const float* Wo = (const float*)d_in[4];
  const void* pos = d_in[5];
  float* out = (float*)d_out;

  const size_t NELEM = (size_t)S_LEN * DMODEL;  // 4M elems

  // ws: 32 MB. d_out doubles as bf16 weight scratch until gemm_out.
  bf16_t* xb  = (bf16_t*)d_ws;   // 8 MB (later Ob)
  bf16_t* Qb  = xb + NELEM;      // 8 MB (later WoB)
  bf16_t* Kb  = Qb + NELEM;      // 8 MB
  bf16_t* Vt  = Kb + NELEM;      // 8 MB
  bf16_t* Ob  = xb;
  bf16_t* WB  = (bf16_t*)d_out;  // [WqB|WkB|WvB] bf16, 6 MB of the 16 MB buffer
  bf16_t* WoB = Qb;              // Wo bf16 in Qb region (free after attn)

  dim3 blk(256);

  // 1) all fp32->bf16 converts for x + Wq/Wk/Wv in ONE launch
  conv_all<<<3584, blk, 0, stream>>>(x, Wq, Wk, Wv, xb, WB);

  // 2) fused QKV GEMM + RoPE (24 x 32 = 768 blocks, 3/CU)
  dim3 gq(3 * DMODEL / QBN, S_LEN / QBM);
  qkv_gemm<<<gq, blk, 0, stream>>>(xb, WB, Qb, Kb, Vt, pos);

  // 3) attention: 16 h x 32 dual-tile blocks, 512 uniform blocks, 2/CU
  attn_kernel<<<NH * 32, blk, 0, stream>>>(Qb, Kb, Vt, Ob);

  // 4) Wo convert (must follow attn: WoB aliases Qb)
  wcvt1<<<WELEM / 2048, blk, 0, stream>>>(Wo, WoB);

  // 5) output GEMM
  dim3 gg(DMODEL / BN, S_LEN / BM);  // (16, 32)
  gemm_out<<<gg, blk, 0, stream>>>(Ob, WoB, out, S_LEN, DMODEL, DMODEL);
}

// Round 9
// 225.716 us; speedup vs baseline: 1.0468x; 1.0468x over previous
//
#include <hip/hip_runtime.h>
#include <hip/hip_bf16.h>
#include <math.h>

typedef __bf16 bf16_t;
typedef __bf16 bf16x8 __attribute__((ext_vector_type(8)));
typedef float floatx4 __attribute__((ext_vector_type(4)));
typedef unsigned int uintx4 __attribute__((ext_vector_type(4)));

#define S_LEN 4096
#define DMODEL 1024
#define NH 16
#define DK 64
#define WELEM (DMODEL * DMODEL)
// 0.125 (1/sqrt(dk)) * log2(e): folded into RoPE'd Q (r13-validated)
#define SCALE_LOG2E 0.1803368801111204f

#define QBM 128
#define QBN 128
#define BM 128
#define BN 64

static __device__ __forceinline__ floatx4 mfma16(bf16x8 a, bf16x8 b, floatx4 c) {
  return __builtin_amdgcn_mfma_f32_16x16x32_bf16(a, b, c, 0, 0, 0);
}

// Raw barrier with lgkm-only wait (attn): NO vmcnt drain.
static __device__ __forceinline__ void barrier_lgkm() {
  __builtin_amdgcn_sched_barrier(0);
  __asm__ volatile("s_waitcnt lgkmcnt(0)" ::: "memory");
  __builtin_amdgcn_s_barrier();
  __builtin_amdgcn_sched_barrier(0);
}

// Counted-vmcnt barrier (GEMMs): wait my oldest staging loads, then sync.
#define VMCNT_BARRIER(N)                                         \
  do {                                                           \
    __builtin_amdgcn_sched_barrier(0);                           \
    __asm__ volatile("s_waitcnt vmcnt(" #N ")" ::: "memory");    \
    __builtin_amdgcn_s_barrier();                                \
    __builtin_amdgcn_sched_barrier(0);                           \
  } while (0)

// global -> LDS direct 16B/lane (wave-uniform LDS base; HW adds lane*16).
typedef __attribute__((address_space(3))) unsigned int lds_u32_t;
typedef __attribute__((address_space(1))) const unsigned int glb_u32_t;
static __device__ __forceinline__ void gll16(const void* g, void* l) {
  __builtin_amdgcn_global_load_lds((glb_u32_t*)g, (lds_u32_t*)l, 16, 0, 0);
}

// bf16 pair pack (truncation — same rounding as the validated >>16 path).
static __device__ __forceinline__ unsigned int packbf(float a, float b) {
  return (__float_as_uint(a) >> 16) | (__float_as_uint(b) & 0xffff0000u);
}

// Paired cross-quad word exchanges (gfx950 permlane*_swap).
static __device__ __forceinline__ void swap32(unsigned int& a, unsigned int& b) {
  auto r = __builtin_amdgcn_permlane32_swap(a, b, false, false);
  a = r[0]; b = r[1];
}
static __device__ __forceinline__ void swap16(unsigned int& a, unsigned int& b) {
  auto r = __builtin_amdgcn_permlane16_swap(a, b, false, false);
  a = r[0]; b = r[1];
}

// Per-tile chunk compute (r21-validated): swapped QK, exp2, causal mask,
// lane-local lsum, bf16 pack + 4x4 cross-quad permlane transpose.
#define QK_SOFTMAX(QF0, QF1, LSUM, PF0, PF1, Q0, MASKED)                     \
  {                                                                          \
    floatx4 s_[4];                                                           \
    __builtin_amdgcn_s_setprio(1);                                           \
    _Pragma("unroll")                                                        \
    for (int f_ = 0; f_ < 4; ++f_) {                                         \
      floatx4 z_ = {0.f, 0.f, 0.f, 0.f};                                     \
      z_ = mfma16(kf[f_][0], QF0, z_);                                       \
      s_[f_] = mfma16(kf[f_][1], QF1, z_);                                   \
    }                                                                        \
    __builtin_amdgcn_s_setprio(0);                                           \
    unsigned int w_[4][2];                                                   \
    _Pragma("unroll")                                                        \
    for (int f_ = 0; f_ < 4; ++f_) {                                         \
      float pe_[4];                                                          \
      _Pragma("unroll")                                                      \
      for (int r_ = 0; r_ < 4; ++r_) {                                       \
        float v_ = __builtin_amdgcn_exp2f(s_[f_][r_]);                       \
        if (MASKED) {                                                        \
          int kv_ = kvb + f_ * 16 + quad * 4 + r_;                           \
          v_ = (kv_ <= (Q0) + lr) ? v_ : 0.f;                                \
        }                                                                    \
        LSUM += v_;                                                          \
        pe_[r_] = v_;                                                        \
      }                                                                      \
      w_[f_][0] = packbf(pe_[0], pe_[1]);                                    \
      w_[f_][1] = packbf(pe_[2], pe_[3]);                                    \
    }                                                                        \
    swap32(w_[0][0], w_[1][0]); swap16(w_[0][0], w_[1][0]);                  \
    swap32(w_[0][1], w_[1][1]); swap16(w_[0][1], w_[1][1]);                  \
    swap32(w_[2][0], w_[3][0]); swap16(w_[2][0], w_[3][0]);                  \
    swap32(w_[2][1], w_[3][1]); swap16(w_[2][1], w_[3][1]);                  \
    uintx4 u0_ = {w_[0][0], w_[0][1], w_[1][0], w_[1][1]};                   \
    uintx4 u1_ = {w_[2][0], w_[2][1], w_[3][0], w_[3][1]};                   \
    __builtin_memcpy(&PF0, &u0_, 16);                                        \
    __builtin_memcpy(&PF1, &u1_, 16);                                        \
  }

// Merged fp32->bf16 convert: blocks 0..2047 convert x (4M elems), blocks
// 2048..3583 convert Wq/Wk/Wv (1M each, 512 blocks per weight).
__global__ __launch_bounds__(256) void conv_all(const float* __restrict__ x,
                                                const float* __restrict__ Wq,
                                                const float* __restrict__ Wk,
                                                const float* __restrict__ Wv,
                                                bf16_t* __restrict__ xb,
                                                bf16_t* __restrict__ WB) {
  const int bid = blockIdx.x;
  const float* src;
  bf16_t* dst;
  size_t i;
  if (bid < 2048) {
    src = x; dst = xb;
    i = (size_t)bid * 2048 + threadIdx.x * 8;
  } else {
    const int w = bid - 2048;
    const int sel = w >> 9;
    src = (sel == 0) ? Wq : ((sel == 1) ? Wk : Wv);
    dst = WB + (size_t)sel * WELEM;
    i = (size_t)(w & 511) * 2048 + threadIdx.x * 8;
  }
  float4 a = *(const float4*)(src + i);
  float4 b = *(const float4*)(src + i + 4);
  bf16x8 v;
  v[0] = (bf16_t)a.x; v[1] = (bf16_t)a.y; v[2] = (bf16_t)a.z; v[3] = (bf16_t)a.w;
  v[4] = (bf16_t)b.x; v[5] = (bf16_t)b.y; v[6] = (bf16_t)b.z; v[7] = (bf16_t)b.w;
  *(bf16x8*)(dst + i) = v;
}

// Single-weight convert (Wo, post-attn — WoB aliases Qb so it cannot run
// before attn finishes reading Q).
__global__ __launch_bounds__(256) void wcvt1(const float* __restrict__ W,
                                             bf16_t* __restrict__ dst) {
  size_t i = ((size_t)blockIdx.x * 256 + threadIdx.x) * 8;
  float4 a = *(const float4*)(W + i);
  float4 b = *(const float4*)(W + i + 4);
  bf16x8 v;
  v[0] = (bf16_t)a.x; v[1] = (bf16_t)a.y; v[2] = (bf16_t)a.z; v[3] = (bf16_t)a.w;
  v[4] = (bf16_t)b.x; v[5] = (bf16_t)b.y; v[6] = (bf16_t)b.z; v[7] = (bf16_t)b.w;
  *(bf16x8*)(dst + i) = v;
}

// FUSED QKV GEMM + RoPE, r25: r24 structure plus
//   (a) 2-D XCD region swizzle: 8 regions of 12 xtiles x 8 mtiles -> per-XCD
//       L2 working set A 2MB + W 3MB (was: all of A, ~70MB refetch).
//   (b) V epilogue via LDS transpose: the old Vo[col*S_LEN+row] 2B scatter
//       caused partial-sector RMW (WRITE_SIZE 107MB vs 24MB ideal, r24 PMC).
//       Now: stage V tile in LDS u16[col][132], write 16B/lane with lane
//       pairs covering full 32B sectors, 256B contiguous per d-row.
__global__ __launch_bounds__(256, 3) void qkv_gemm(const bf16_t* __restrict__ A,
                                                   const bf16_t* __restrict__ WB,
                                                   bf16_t* __restrict__ Qo,
                                                   bf16_t* __restrict__ Ko,
                                                   bf16_t* __restrict__ Vo,
                                                   const void* __restrict__ posv) {
  // 3 slots x {A[128][64B] | B[128][64B]} = 3 x 16 KB; V-transpose reuses it
  __shared__ __align__(16) unsigned char smem[49152];

  const int tid  = threadIdx.x;
  const int wid  = tid >> 6;
  const int lane = tid & 63;
  const int lr   = lane & 15;
  const int quad = lane >> 4;
  const int wm = wid >> 1, wn = wid & 1;

  // bijective 2-D region swizzle over the (24 x 32) grid
  const int flat = blockIdx.x + blockIdx.y * 24;
  const int xcd  = flat & 7;
  const int idx  = flat >> 3;              // 0..95
  const int xt   = (xcd >> 2) * 12 + idx % 12;   // 0..23
  const int mt   = (xcd & 3) * 8 + idx / 12;     // 0..31
  const int sel  = xt >> 3;                // 0=Q, 1=K, 2=V
  const int n0   = (xt & 7) * QBN;
  const int m0   = mt * QBM;
  const bf16_t* Bsrc = WB + (size_t)sel * WELEM;

  const int mat  = wid >> 1;                 // 0=A, 1=B
  const int lrow = lane >> 2;                // 0..15
  const int swzl = ((lane & 3) * 16) ^ ((lrow & 3) << 4);
  const unsigned char* gbase =
      (const unsigned char*)(mat ? Bsrc : A) +
      (size_t)((mat ? n0 : m0) + (wid & 1) * 64 + lrow) * (DMODEL * 2) + swzl;
  const int lds_w = mat * 8192 + (wid & 1) * 4096;  // + k*1024 + slot*16384

  floatx4 acc[4][4];
#pragma unroll
  for (int i = 0; i < 4; ++i)
#pragma unroll
    for (int j = 0; j < 4; ++j) acc[i][j] = floatx4{0.f, 0.f, 0.f, 0.f};

  // prologue: K-steps 0,1 into slots 0,1
#pragma unroll
  for (int st = 0; st < 2; ++st) {
    const unsigned char* gs = gbase + st * 64;
    unsigned char* ls = smem + st * 16384 + lds_w;
#pragma unroll
    for (int k = 0; k < 4; ++k)
      gll16(gs + (size_t)k * (16 * 2048), ls + k * 1024);
  }

  const int frsw = 16 * (quad ^ (lr & 3));
  int csl = 0, isl = 2;
  for (int it = 0; it < 32; ++it) {
    VMCNT_BARRIER(4);   // my step-it loads landed; barrier -> everyone's

    {  // issue step it+2 into slot isl (freed by the barrier above)
      int sd = it + 2; if (sd > 31) sd = 31;
      const unsigned char* gs = gbase + sd * 64;
      unsigned char* ls = smem + isl * 16384 + lds_w;
#pragma unroll
      for (int k = 0; k < 4; ++k)
        gll16(gs + (size_t)k * (16 * 2048), ls + k * 1024);
    }

    const unsigned char* As_ = smem + csl * 16384;
    bf16x8 af[4], bfr[4];
#pragma unroll
    for (int i = 0; i < 4; ++i)
      af[i] = *(const bf16x8*)(As_ + (wm * 64 + i * 16 + lr) * 64 + frsw);
#pragma unroll
    for (int j = 0; j < 4; ++j)
      bfr[j] = *(const bf16x8*)(As_ + 8192 + (wn * 64 + j * 16 + lr) * 64 + frsw);

    __builtin_amdgcn_s_setprio(1);
#pragma unroll
    for (int i = 0; i < 4; ++i)
#pragma unroll
      for (int j = 0; j < 4; ++j)
        acc[i][j] = mfma16(af[i], bfr[j], acc[i][j]);
    __builtin_amdgcn_s_setprio(0);

    csl = (csl == 2) ? 0 : csl + 1;
    isl = (isl == 2) ? 0 : isl + 1;
  }

  if (sel < 2) {
    // ---- fused RoPE epilogue (rope_kernel math, r13-validated) ----
    bf16_t* Cn = (sel == 0) ? Qo : Ko;
    const long long* p64 = (const long long*)posv;
    const int*       p32 = (const int*)posv;
    unsigned long long w0 = (unsigned long long)p64[0];
    unsigned long long w1 = (unsigned long long)p64[1];
    const bool is64 = ((w0 >> 32) == 0ull) && ((w1 >> 32) == 0ull);
    const float qs  = (sel == 0) ? SCALE_LOG2E : 1.0f;
    const float sgn = (lane & 1) ? 1.0f : -1.0f;

    float invf[4];
#pragma unroll
    for (int j = 0; j < 4; ++j)
      invf[j] = expf(-(float)(j * 8 + (lr >> 1)) * (9.210340371976184f / 32.0f));

#pragma unroll
    for (int i = 0; i < 4; ++i) {
#pragma unroll
      for (int r = 0; r < 4; ++r) {
        const int row = m0 + wm * 64 + i * 16 + quad * 4 + r;
        long long v64 = p64[is64 ? row : 0];
        const float p = is64 ? (float)v64 : (float)p32[row];
#pragma unroll
        for (int j = 0; j < 4; ++j) {
          float my    = acc[i][j][r];
          float other = __shfl_xor(my, 1, 64);
          float sn, cs;
          sincosf(p * invf[j], &sn, &cs);
          float v = (my * cs + sgn * other * sn) * qs;
          int col = n0 + wn * 64 + j * 16 + lr;
          Cn[(size_t)row * DMODEL + col] = (bf16_t)v;
        }
      }
    }
  } else {
    // ---- V epilogue: LDS transpose -> full-sector vectorized stores ----
    __syncthreads();   // all waves done with ring; drains in-flight gll's
    unsigned short* Vs = (unsigned short*)smem;   // [128 cols][pitch 132]
#pragma unroll
    for (int i = 0; i < 4; ++i)
#pragma unroll
      for (int j = 0; j < 4; ++j) {
        const int row = wm * 64 + i * 16 + quad * 4;   // local s-row base
        const int col = wn * 64 + j * 16 + lr;         // local d-col
        unsigned int lo, hi;
        {
          bf16_t b0 = (bf16_t)acc[i][j][0], b1 = (bf16_t)acc[i][j][1];
          unsigned short u0, u1;
          __builtin_memcpy(&u0, &b0, 2); __builtin_memcpy(&u1, &b1, 2);
          lo = (unsigned)u0 | ((unsigned)u1 << 16);
        }
        {
          bf16_t b2 = (bf16_t)acc[i][j][2], b3 = (bf16_t)acc[i][j][3];
          unsigned short u2, u3;
          __builtin_memcpy(&u2, &b2, 2); __builtin_memcpy(&u3, &b3, 2);
          hi = (unsigned)u2 | ((unsigned)u3 << 16);
        }
        uint2 pk = {lo, hi};
        *(uint2*)(Vs + col * 132 + row) = pk;   // 8B, aligned (row mult 4)
      }
    __syncthreads();

    // lane pair (2c, 2c+1) covers col c's 256B run; 16B/lane/instr with the
    // pair completing each 32B sector (no partial-sector RMW).
    const int col = tid >> 1, hb = tid & 1;
    bf16_t* vgp = Vo + (size_t)(n0 + col) * S_LEN + m0 + hb * 8;
    const unsigned short* vsp = Vs + col * 132 + hb * 8;
#pragma unroll
    for (int k = 0; k < 8; ++k) {
      uint2 a = *(const uint2*)(vsp + 16 * k);
      uint2 b = *(const uint2*)(vsp + 16 * k + 4);
      uintx4 w = {a.x, a.y, b.x, b.y};
      *(uintx4*)(vgp + 16 * k) = w;
    }
  }
}

// Final GEMM, r25: gll + 3-slot ring + counted vmcnt(3) + 2-D XCD region
// swizzle (8 regions of 8 xtiles x 8 mtiles over the 16x32 grid).
__global__ __launch_bounds__(256, 2) void gemm_out(const bf16_t* __restrict__ A,
                                                   const bf16_t* __restrict__ B,
                                                   float* __restrict__ C,
                                                   int M, int N, int Kd) {
  __shared__ __align__(16) unsigned char smem[36864];

  const int tid  = threadIdx.x;
  const int wid  = tid >> 6;
  const int lane = tid & 63;
  const int lr   = lane & 15;
  const int quad = lane >> 4;
  const int wm = wid >> 1, wn = wid & 1;

  const int flat = blockIdx.x + blockIdx.y * 16;
  const int xcd  = flat & 7;
  const int idx  = flat >> 3;              // 0..63
  const int xt   = (xcd & 1) * 8 + idx % 8;     // 0..15
  const int mt   = (xcd >> 1) * 8 + idx / 8;    // 0..31
  const int m0 = mt * BM;
  const int n0 = xt * BN;
  const int NIT = Kd >> 5;                 // 32

  const int lrow = lane >> 2;
  const int swzl = ((lane & 3) * 16) ^ ((lrow & 3) << 4);
  const unsigned char* gk[3];
  int lo[3];
#pragma unroll
  for (int k = 0; k < 3; ++k) {
    int id = wid * 3 + k;
    bool mb = id >= 8;
    int r = (id - (mb ? 8 : 0)) * 16 + lrow;
    gk[k] = (const unsigned char*)(mb ? B : A) +
            (size_t)((mb ? n0 : m0) + r) * ((size_t)Kd * 2) + swzl;
    lo[k] = mb ? (8192 + (id - 8) * 1024) : (id * 1024);
  }

  floatx4 acc[4][2];
#pragma unroll
  for (int i = 0; i < 4; ++i)
#pragma unroll
    for (int j = 0; j < 2; ++j) acc[i][j] = floatx4{0.f, 0.f, 0.f, 0.f};

#pragma unroll
  for (int st = 0; st < 2; ++st) {
    unsigned char* ls = smem + st * 12288;
#pragma unroll
    for (int k = 0; k < 3; ++k)
      gll16(gk[k] + st * 64, ls + lo[k]);
  }

  const int frsw = 16 * (quad ^ (lr & 3));
  int csl = 0, isl = 2;
  for (int it = 0; it < NIT; ++it) {
    VMCNT_BARRIER(3);

    {
      int sd = it + 2; if (sd > NIT - 1) sd = NIT - 1;
      unsigned char* ls = smem + isl * 12288;
#pragma unroll
      for (int k = 0; k < 3; ++k)
        gll16(gk[k] + sd * 64, ls + lo[k]);
    }

    const unsigned char* As_ = smem + csl * 12288;
    bf16x8 af[4], bfr[2];
#pragma unroll
    for (int i = 0; i < 4; ++i)
      af[i] = *(const bf16x8*)(As_ + (wm * 64 + i * 16 + lr) * 64 + frsw);
#pragma unroll
    for (int j = 0; j < 2; ++j)
      bfr[j] = *(const bf16x8*)(As_ + 8192 + (wn * 32 + j * 16 + lr) * 64 + frsw);

    __builtin_amdgcn_s_setprio(1);
#pragma unroll
    for (int i = 0; i < 4; ++i)
#pragma unroll
      for (int j = 0; j < 2; ++j)
        acc[i][j] = mfma16(af[i], bfr[j], acc[i][j]);
    __builtin_amdgcn_s_setprio(0);

    csl = (csl == 2) ? 0 : csl + 1;
    isl = (isl == 2) ? 0 : isl + 1;
  }

#pragma unroll
  for (int i = 0; i < 4; ++i)
#pragma unroll
    for (int j = 0; j < 2; ++j)
#pragma unroll
      for (int r = 0; r < 4; ++r) {
        int row = m0 + wm * 64 + i * 16 + quad * 4 + r;
        int col = n0 + wn * 32 + j * 16 + lr;
        C[(size_t)row * N + col] = acc[i][j][r];
      }
}

// Flash attention, r22 structure (UNCHANGED, validated): dual-tile waves,
// in-register P transpose, raw lgkm barriers, reg-prefetch staging.
__global__ __launch_bounds__(256, 2) void attn_kernel(const bf16_t* __restrict__ Q,
                                                      const bf16_t* __restrict__ Kb,
                                                      const bf16_t* __restrict__ Vt,
                                                      bf16_t* __restrict__ O) {
  __shared__ __align__(16) unsigned char smem[32768];

  const int tid  = threadIdx.x;
  const int wid  = tid >> 6;
  const int lane = tid & 63;
  const int lr   = lane & 15;
  const int quad = lane >> 4;

  const int bid = blockIdx.x;
  const int h   = bid & 15;
  const int pid = bid >> 4;    // 0..31

  const int pA = 63 - pid, pB = pid;
  const int maxcA = pA + 1;
  const int maxcB = pB + 1;
  const int nit   = (maxcA + 1) >> 1;
  const int q0A   = pA * 64 + wid * 16;
  const int q0B   = pB * 64 + wid * 16;

  const bf16_t* Kh = Kb + h * DK;
  const bf16_t* Vh = Vt + (size_t)h * DK * S_LEN;

  const int r0  = tid >> 3;
  const int ke  = (tid & 7) * 8;
  const int ls0 = (r0 * 128 + (tid & 7) * 16) ^ ((r0 & 7) << 4);
  const int ls1 = ls0 + 4096;
  const int sw  = (lr & 7) << 4;

  bf16x8 qfA0, qfA1, qfB0, qfB1;
  {
    const bf16_t* Qp = Q + (size_t)(q0A + lr) * DMODEL + h * DK + quad * 8;
    qfA0 = *(const bf16x8*)(Qp);
    qfA1 = *(const bf16x8*)(Qp + 32);
    const bf16_t* Qq = Q + (size_t)(q0B + lr) * DMODEL + h * DK + quad * 8;
    qfB0 = *(const bf16x8*)(Qq);
    qfB1 = *(const bf16x8*)(Qq + 32);
  }

  floatx4 oA[4], oB[4];
#pragma unroll
  for (int dt = 0; dt < 4; ++dt) {
    oA[dt] = floatx4{0.f, 0.f, 0.f, 0.f};
    oB[dt] = floatx4{0.f, 0.f, 0.f, 0.f};
  }
  float lsumA = 0.f, lsumB = 0.f;

  bf16x8 kr[2][2], vr[2][2];
#pragma unroll
  for (int j = 0; j < 2; ++j) {
    const bf16_t* kg = Kh + (size_t)(j * 64 + r0) * DMODEL + ke;
    const bf16_t* vg = Vh + (size_t)r0 * S_LEN + j * 64 + ke;
    kr[j][0] = *(const bf16x8*)(kg);
    kr[j][1] = *(const bf16x8*)(kg + (size_t)32 * DMODEL);
    vr[j][0] = *(const bf16x8*)(vg);
    vr[j][1] = *(const bf16x8*)(vg + (size_t)32 * S_LEN);
  }

  for (int i = 0; i < nit; ++i) {
    barrier_lgkm();
#pragma unroll
    for (int j = 0; j < 2; ++j) {
      unsigned char* Kd = smem + j * 16384;
      *(bf16x8*)(Kd + ls0)        = kr[j][0];
      *(bf16x8*)(Kd + ls1)        = kr[j][1];
      *(bf16x8*)(Kd + 8192 + ls0) = vr[j][0];
      *(bf16x8*)(Kd + 8192 + ls1) = vr[j][1];
    }
    {
      int cn0 = 2 * i + 2; if (cn0 > maxcA - 1) cn0 = maxcA - 1;
      int cn1 = 2 * i + 3; if (cn1 > maxcA - 1) cn1 = maxcA - 1;
      const int cs0[2] = {cn0, cn1};
#pragma unroll
      for (int j = 0; j < 2; ++j) {
        const bf16_t* kg = Kh + (size_t)(cs0[j] * 64 + r0) * DMODEL + ke;
        const bf16_t* vg = Vh + (size_t)r0 * S_LEN + cs0[j] * 64 + ke;
        kr[j][0] = *(const bf16x8*)(kg);
        kr[j][1] = *(const bf16x8*)(kg + (size_t)32 * DMODEL);
        vr[j][0] = *(const bf16x8*)(vg);
        vr[j][1] = *(const bf16x8*)(vg + (size_t)32 * S_LEN);
      }
    }
    barrier_lgkm();

#pragma unroll
    for (int j = 0; j < 2; ++j) {
      const int c = 2 * i + j;
      if (c < maxcA) {
        const int kvb = c * 64;
        unsigned char* Kbuf = smem + j * 16384;
        unsigned char* Vbuf = Kbuf + 8192;

        bf16x8 kf[4][2];
#pragma unroll
        for (int f = 0; f < 4; ++f) {
          const int rowb = (f * 16 + lr) * 128;
          kf[f][0] = *(const bf16x8*)(Kbuf + rowb + ((quad * 16) ^ sw));
          kf[f][1] = *(const bf16x8*)(Kbuf + rowb + ((quad * 16 + 64) ^ sw));
        }

        bf16x8 pfA0, pfA1;
        QK_SOFTMAX(qfA0, qfA1, lsumA, pfA0, pfA1, q0A, (c == maxcA - 1));

        const bool doB = (c < maxcB);
        bf16x8 pfB0, pfB1;
        if (doB) {
          QK_SOFTMAX(qfB0, qfB1, lsumB, pfB0, pfB1, q0B, (c == maxcB - 1));
        }

        __builtin_amdgcn_s_setprio(1);
        if (doB) {
#pragma unroll
          for (int dt = 0; dt < 4; ++dt) {
            const int rowb = (dt * 16 + lr) * 128;
            bf16x8 v0 = *(const bf16x8*)(Vbuf + rowb + ((quad * 16) ^ sw));
            bf16x8 v1 = *(const bf16x8*)(Vbuf + rowb + ((quad * 16 + 64) ^ sw));
            oA[dt] = mfma16(pfA0, v0, oA[dt]);
            oA[dt] = mfma16(pfA1, v1, oA[dt]);
            oB[dt] = mfma16(pfB0, v0, oB[dt]);
            oB[dt] = mfma16(pfB1, v1, oB[dt]);
          }
        } else {
#pragma unroll
          for (int dt = 0; dt < 4; ++dt) {
            const int rowb = (dt * 16 + lr) * 128;
            bf16x8 v0 = *(const bf16x8*)(Vbuf + rowb + ((quad * 16) ^ sw));
            bf16x8 v1 = *(const bf16x8*)(Vbuf + rowb + ((quad * 16 + 64) ^ sw));
            oA[dt] = mfma16(pfA0, v0, oA[dt]);
            oA[dt] = mfma16(pfA1, v1, oA[dt]);
          }
        }
        __builtin_amdgcn_s_setprio(0);
      }
    }
  }

  lsumA += __shfl_xor(lsumA, 16, 64);
  lsumA += __shfl_xor(lsumA, 32, 64);
  lsumB += __shfl_xor(lsumB, 16, 64);
  lsumB += __shfl_xor(lsumB, 32, 64);

  float invA[4], invB[4];
#pragma unroll
  for (int r = 0; r < 4; ++r) {
    invA[r] = 1.0f / __shfl(lsumA, quad * 4 + r, 64);
    invB[r] = 1.0f / __shfl(lsumB, quad * 4 + r, 64);
  }

#pragma unroll
  for (int dt = 0; dt < 4; ++dt)
#pragma unroll
    for (int r = 0; r < 4; ++r) {
      int rowA = q0A + quad * 4 + r;
      O[(size_t)rowA * DMODEL + h * DK + dt * 16 + lr] =
          (bf16_t)(oA[dt][r] * invA[r]);
      int rowB = q0B + quad * 4 + r;
      O[(size_t)rowB * DMODEL + h * DK + dt * 16 + lr] =
          (bf16_t)(oB[dt][r] * invB[r]);
    }
}

extern "C" void kernel_launch(void* const* d_in, const int* in_sizes, int n_in,
                              void* d_out, int out_size, void* d_ws, size_t ws_size,
                              hipStream_t stream) {
  const float* x  = (const float*)d_in[0];
  const float* Wq = (const float*)d_in[1];
  const float* Wk = (const float*)d_in[2];
  const float* Wv = (const float*)d_in[3];
  const float* Wo = (const float*)d_in[4];
  const void* pos = d_in[5];
  float* out = (float*)d_out;

  const size_t NELEM = (size_t)S_LEN * DMODEL;  // 4M elems

  // ws: 32 MB. d_out doubles as bf16 weight scratch until gemm_out.
  bf16_t* xb  = (bf16_t*)d_ws;   // 8 MB (later Ob)
  bf16_t* Qb  = xb + NELEM;      // 8 MB (later WoB)
  bf16_t* Kb  = Qb + NELEM;      // 8 MB
  bf16_t* Vt  = Kb + NELEM;      // 8 MB
  bf16_t* Ob  = xb;
  bf16_t* WB  = (bf16_t*)d_out;  // [WqB|WkB|WvB] bf16, 6 MB of the 16 MB buffer
  bf16_t* WoB = Qb;              // Wo bf16 in Qb region (free after attn)

  dim3 blk(256);

  // 1) all fp32->bf16 converts for x + Wq/Wk/Wv in ONE launch
  conv_all<<<3584, blk, 0, stream>>>(x, Wq, Wk, Wv, xb, WB);

  // 2) fused QKV GEMM + RoPE (24 x 32 = 768 blocks, 3/CU, XCD-regioned)
  dim3 gq(3 * DMODEL / QBN, S_LEN / QBM);
  qkv_gemm<<<gq, blk, 0, stream>>>(xb, WB, Qb, Kb, Vt, pos);

  // 3) attention: 16 h x 32 dual-tile blocks, 512 uniform blocks, 2/CU
  attn_kernel<<<NH * 32, blk, 0, stream>>>(Qb, Kb, Vt, Ob);

  // 4) Wo convert (must follow attn: WoB aliases Qb)
  wcvt1<<<WELEM / 2048, blk, 0, stream>>>(Wo, WoB);

  // 5) output GEMM (XCD-regioned)
  dim3 gg(DMODEL / BN, S_LEN / BM);  // (16, 32)
  gemm_out<<<gg, blk, 0, stream>>>(Ob, WoB, out, S_LEN, DMODEL, DMODEL);
}